// Round 4
// baseline (485.785 us; speedup 1.0000x reference)
//
#include <hip/hip_runtime.h>
#include <hip/hip_bf16.h>

#define L_SZ 200
#define RB 8

typedef __attribute__((ext_vector_type(8))) short short8;   // 8 bf16 = 4 VGPRs (MFMA A/B frag)
typedef __attribute__((ext_vector_type(4))) float floatx4;  // MFMA C/D frag

__device__ __forceinline__ unsigned short f2bf(float f) {
    unsigned int u = __float_as_uint(f);
    unsigned int r = (u + 0x7fffu + ((u >> 16) & 1u)) >> 16;
    return (unsigned short)r;
}
__device__ __forceinline__ float bf2f(unsigned short h) {
    return __uint_as_float(((unsigned int)h) << 16);
}
__device__ __forceinline__ float wave_sum64(float v) {
    #pragma unroll
    for (int m = 1; m <= 32; m <<= 1) v += __shfl_xor(v, m, 64);
    return v;
}
__device__ __forceinline__ float wave_max64(float v) {
    #pragma unroll
    for (int m = 1; m <= 32; m <<= 1) v = fmaxf(v, __shfl_xor(v, m, 64));
    return v;
}
__device__ __forceinline__ unsigned int pk2(float a, float b) {
    return ((unsigned int)f2bf(b) << 16) | (unsigned int)f2bf(a);
}

// One block per batch element, 4 waves. Layer0 folded to 64x64 W_eff.
// R4: A-fragments gathered DIRECTLY from hist_W into registers (lane (c,q) of
// wave w owns rows mt*16+c); the packed bf16 doubles as the Hs write for
// pooling. seq per-lane from global. One barrier before the MFMA loop, none
// inside. Hs uses 16B-group XOR swizzle: group g' = g ^ (row&7) -> b128 writes
// are bank-optimal, pooled dword reads conflict-free.
__global__ __launch_bounds__(256, 4) void attn_kernel(
    const int* __restrict__ item_id, const int* __restrict__ hist_seq,
    const float* __restrict__ item_W, const float* __restrict__ hist_W,
    const float* __restrict__ aW0, const float* __restrict__ ab0,
    const float* __restrict__ aW1, const float* __restrict__ ab1,
    const float* __restrict__ aW2, const float* __restrict__ ab2,
    float* __restrict__ pooled_ws)
{
    __shared__ __align__(16) unsigned char smem[35136];
    unsigned short* Hs = (unsigned short*)(smem);           // 200 x 64 bf16 = 25600 B (swizzled)
    unsigned short* BB = (unsigned short*)(smem + 25600);   // 8192 B: WeT -> scr -> pools
    float* scores = (float*)(smem + 33792);                 // 200 f32
    float* cbp    = (float*)(smem + 34592);                 // 128 f32 cb partials
    float* red    = (float*)(smem + 35104);                 // 8 f32

    const int tid  = threadIdx.x;
    const int w    = tid >> 6;
    const int lane = tid & 63;
    const int c    = lane & 15, q = lane >> 4;
    const int b    = blockIdx.x;
    const int item = item_id[b];
    const float* iW = item_W + (size_t)item * 64;

    // wave w owns tiles mt = w, w+4, w+8 (+12 for wave 0); 13 tiles of 16 rows
    const int ntile = (w == 0) ? 4 : 3;

    // ---- A-operand gathers: straight to registers, all in flight early ----
    int    seqr[4];
    float4 g0[4][2], g1[4][2];
    #pragma unroll
    for (int t = 0; t < 4; ++t) {
        if (t < ntile) {
            const int mt  = w + 4 * t;
            const int row = mt * 16 + c;
            const int rc  = (row < L_SZ) ? row : (L_SZ - 1);
            seqr[t] = hist_seq[b * L_SZ + rc];
            const float* hrow = hist_W + (size_t)seqr[t] * 64;
            #pragma unroll
            for (int ks = 0; ks < 2; ++ks) {
                g0[t][ks] = *(const float4*)(hrow + ks * 32 + q * 8);
                g1[t][ks] = *(const float4*)(hrow + ks * 32 + q * 8 + 4);
            }
        }
    }

    // ---- bW1 direct register build (aW1 L2-hot): k = ks*32+q*8+i, n = nt*16+c ----
    short8 bW1[2][2];
    #pragma unroll
    for (int nt = 0; nt < 2; ++nt)
        #pragma unroll
        for (int ks = 0; ks < 2; ++ks) {
            unsigned short tmp[8];
            #pragma unroll
            for (int i = 0; i < 8; ++i)
                tmp[i] = f2bf(aW1[(ks * 32 + q * 8 + i) * 32 + nt * 16 + c]);
            bW1[nt][ks] = *(short8*)tmp;
        }
    float ab1r[2], aw2r[2];
    #pragma unroll
    for (int nt = 0; nt < 2; ++nt) {
        ab1r[nt] = ab1[nt * 16 + c];
        aw2r[nt] = aW2[nt * 16 + c];
    }
    const float ab2s = ab2[0];

    // ---- WeT cooperative build into BB (swizzled), iemb from global ----
    for (int u = tid; u < 512; u += 256) {
        int j = u >> 3, k8 = u & 7;
        float4 ia = *(const float4*)(iW + k8 * 8);
        float4 ib = *(const float4*)(iW + k8 * 8 + 4);
        float ie[8] = {ia.x, ia.y, ia.z, ia.w, ib.x, ib.y, ib.z, ib.w};
        float v[8];
        #pragma unroll
        for (int i = 0; i < 8; ++i) {
            int k = k8 * 8 + i;
            v[i] = aW0[k * 64 + j] + aW0[(192 + k) * 64 + j]
                 + ie[i] * aW0[(128 + k) * 64 + j];
        }
        uint4 pk;
        pk.x = pk2(v[0], v[1]); pk.y = pk2(v[2], v[3]);
        pk.z = pk2(v[4], v[5]); pk.w = pk2(v[6], v[7]);
        *(uint4*)(BB + j * 64 + (k8 ^ (j & 7)) * 8) = pk;
    }
    // ---- cb partials (waves 0,1): cbp[j] halves of sum_k iemb[k]*(A1-A3)[k][j] ----
    if (w < 2) {
        float cpart = 0.f;
        #pragma unroll 4
        for (int t = 0; t < 32; ++t) {
            int k = w * 32 + t;
            cpart = fmaf(iW[k], aW0[(64 + k) * 64 + lane] - aW0[(192 + k) * 64 + lane], cpart);
        }
        cbp[w * 64 + lane] = cpart;
    }

    // ---- pack A-frags; same bytes -> Hs (swizzled) for pooling ----
    short8 afr[4][2];
    #pragma unroll
    for (int t = 0; t < 4; ++t) {
        if (t < ntile) {
            const int mt  = w + 4 * t;
            const int row = mt * 16 + c;
            #pragma unroll
            for (int ks = 0; ks < 2; ++ks) {
                uint4 pk;
                pk.x = pk2(g0[t][ks].x, g0[t][ks].y);
                pk.y = pk2(g0[t][ks].z, g0[t][ks].w);
                pk.z = pk2(g1[t][ks].x, g1[t][ks].y);
                pk.w = pk2(g1[t][ks].z, g1[t][ks].w);
                afr[t][ks] = *(short8*)&pk;
                if (row < L_SZ)
                    *(uint4*)(Hs + row * 64 + ((ks * 4 + q) ^ (row & 7)) * 8) = pk;
            }
        }
    }
    __syncthreads();

    // ---- hoist bW from swizzled WeT; per-lane cbr (no extra barrier) ----
    short8 bW[4][2];
    #pragma unroll
    for (int nt = 0; nt < 4; ++nt)
        #pragma unroll
        for (int ks = 0; ks < 2; ++ks)
            bW[nt][ks] = *(const short8*)(BB + (nt * 16 + c) * 64
                                             + ((4 * ks + q) ^ (c & 7)) * 8);
    float cbr[4];
    #pragma unroll
    for (int nt = 0; nt < 4; ++nt) {
        int j = nt * 16 + c;
        cbr[nt] = ab0[j] + cbp[j] + cbp[64 + j];
    }
    __syncthreads();   // protect BB: all hoists done before any scr write

    unsigned short* scrw = BB + w * (16 * 64);
    const floatx4 zf = {0.f, 0.f, 0.f, 0.f};

    // ---- main loop: NO barriers. L0 MFMA -> scr -> L1 MFMA -> score ----
    #pragma unroll
    for (int t = 0; t < 4; ++t) {
        if (t >= ntile) break;
        const int mt = w + 4 * t;
        const int rowbase = mt * 16;
        floatx4 acc0[4] = {zf, zf, zf, zf};
        #pragma unroll
        for (int ks = 0; ks < 2; ++ks) {
            acc0[0] = __builtin_amdgcn_mfma_f32_16x16x32_bf16(afr[t][ks], bW[0][ks], acc0[0], 0, 0, 0);
            acc0[1] = __builtin_amdgcn_mfma_f32_16x16x32_bf16(afr[t][ks], bW[1][ks], acc0[1], 0, 0, 0);
            acc0[2] = __builtin_amdgcn_mfma_f32_16x16x32_bf16(afr[t][ks], bW[2][ks], acc0[2], 0, 0, 0);
            acc0[3] = __builtin_amdgcn_mfma_f32_16x16x32_bf16(afr[t][ks], bW[3][ks], acc0[3], 0, 0, 0);
        }
        // epilogue: +cb, relu, bf16; C-layout (col=c,row=q*4+r) -> swizzled scr
        #pragma unroll
        for (int nt = 0; nt < 4; ++nt)
            #pragma unroll
            for (int r = 0; r < 4; ++r) {
                float h = fmaxf(acc0[nt][r] + cbr[nt], 0.f);
                int row = q * 4 + r;
                int gp = (2 * nt + (c >> 3)) ^ (row & 7);
                scrw[row * 64 + gp * 8 + (c & 7)] = f2bf(h);
            }
        floatx4 acc1[2] = {zf, zf};
        #pragma unroll
        for (int ks = 0; ks < 2; ++ks) {
            short8 a1 = *(const short8*)(scrw + c * 64 + ((4 * ks + q) ^ (c & 7)) * 8);
            acc1[0] = __builtin_amdgcn_mfma_f32_16x16x32_bf16(a1, bW1[0][ks], acc1[0], 0, 0, 0);
            acc1[1] = __builtin_amdgcn_mfma_f32_16x16x32_bf16(a1, bW1[1][ks], acc1[1], 0, 0, 0);
        }
        // layer2: relu -> *aW2 -> butterfly over 16 col-lanes (all lanes get sum)
        float s[4];
        #pragma unroll
        for (int r = 0; r < 4; ++r)
            s[r] = fmaxf(acc1[0][r] + ab1r[0], 0.f) * aw2r[0]
                 + fmaxf(acc1[1][r] + ab1r[1], 0.f) * aw2r[1];
        #pragma unroll
        for (int m = 1; m <= 8; m <<= 1)
            #pragma unroll
            for (int r = 0; r < 4; ++r) s[r] += __shfl_xor(s[r], m, 64);
        // lane's own row (rowbase+c) lives at (q'=c>>2, r'=c&3); fetch via shfl
        int rsel = c & 3;
        float sv = (rsel == 0) ? s[0] : (rsel == 1) ? s[1] : (rsel == 2) ? s[2] : s[3];
        sv = __shfl(sv, ((c >> 2) << 4) | c, 64);
        if (q == 0) {
            int l = rowbase + c;
            if (l < L_SZ)
                scores[l] = (seqr[t] == 0) ? -1.0e9f : (sv + ab2s);
        }
    }
    __syncthreads();

    // ---- masked softmax over 200 scores ----
    float s0 = (tid < L_SZ) ? scores[tid] : -3.0e38f;
    float mx = wave_max64(s0);
    if (lane == 0) red[w] = mx;
    __syncthreads();
    mx = fmaxf(fmaxf(red[0], red[1]), fmaxf(red[2], red[3]));
    float e = (tid < L_SZ) ? __expf(s0 - mx) : 0.f;
    float sm = wave_sum64(e);
    if (lane == 0) red[4 + w] = sm;
    __syncthreads();
    const float winv = 1.f / ((red[4] + red[5]) + (red[6] + red[7]));
    if (tid < L_SZ) scores[tid] = e * winv;
    __syncthreads();

    // ---- pooled[j] = sum_l w_l * H[l][j]; swizzle-aware dword reads ----
    float* pools = (float*)BB;   // scr dead now
    {
        int g  = (w << 1) | (lane >> 5);
        int jj = lane & 31;
        int l0 = g * 26, l1 = (l0 + 26 < L_SZ) ? l0 + 26 : L_SZ;
        float p0 = 0.f, p1 = 0.f;
        for (int l = l0; l < l1; ++l) {
            float wt = scores[l];
            int grp = (jj >> 2) ^ (l & 7);
            unsigned int pv = *(const unsigned int*)(Hs + l * 64 + grp * 8 + ((2 * jj) & 7));
            p0 = fmaf(wt, bf2f((unsigned short)(pv & 0xffffu)), p0);
            p1 = fmaf(wt, bf2f((unsigned short)(pv >> 16)), p1);
        }
        float2 pp = {p0, p1};
        *(float2*)&pools[g * 64 + jj * 2] = pp;
    }
    __syncthreads();
    if (tid < 64) {
        float sum = 0.f;
        #pragma unroll
        for (int g = 0; g < 8; ++g) sum += pools[g * 64 + tid];
        pooled_ws[(size_t)b * 64 + tid] = sum;
    }
}

// Main MLP: 244 -> 256 -> 128 -> 1 -> sigmoid. One block per RB=8 rows.
__global__ __launch_bounds__(256) void mlp_kernel(
    const int* __restrict__ user_id, const int* __restrict__ item_id,
    const int* __restrict__ item_cat, const int* __restrict__ item_dur,
    const float* __restrict__ user_dense, const float* __restrict__ item_dense,
    const float* __restrict__ user_W, const float* __restrict__ item_W,
    const float* __restrict__ cat_W, const float* __restrict__ dur_W,
    const float* __restrict__ mW0, const float* __restrict__ mb0,
    const float* __restrict__ mW1, const float* __restrict__ mb1,
    const float* __restrict__ mW2, const float* __restrict__ mb2,
    const float* __restrict__ pooled_ws, float* __restrict__ out)
{
    __shared__ __align__(16) float xT[244][RB];
    __shared__ __align__(16) float h0T[256][RB];
    __shared__ __align__(16) float h1T[128][RB];
    __shared__ __align__(16) float part[128][RB];

    const int tid = threadIdx.x;
    const int b0 = blockIdx.x * RB;

    for (int idx = tid; idx < 244 * RB; idx += 256) {
        int r = idx / 244;
        int c = idx - r * 244;
        int b = b0 + r;
        float v;
        if (c < 64)       v = user_W[(size_t)user_id[b] * 64 + c];
        else if (c < 128) v = item_W[(size_t)item_id[b] * 64 + (c - 64)];
        else if (c < 144) v = cat_W[item_cat[b] * 16 + (c - 128)];
        else if (c < 152) v = dur_W[item_dur[b] * 8 + (c - 144)];
        else if (c < 177) v = user_dense[b * 25 + (c - 152)];
        else if (c < 180) v = item_dense[b * 3 + (c - 177)];
        else              v = pooled_ws[(size_t)b * 64 + (c - 180)];
        xT[c][r] = v;
    }
    __syncthreads();

    {
        float acc[RB];
        const float bias = mb0[tid];
        #pragma unroll
        for (int r = 0; r < RB; ++r) acc[r] = bias;
        #pragma unroll 4
        for (int k = 0; k < 244; ++k) {
            float wk = mW0[k * 256 + tid];
            float4 xa = *(const float4*)&xT[k][0];
            float4 xb = *(const float4*)&xT[k][4];
            acc[0] = fmaf(wk, xa.x, acc[0]);
            acc[1] = fmaf(wk, xa.y, acc[1]);
            acc[2] = fmaf(wk, xa.z, acc[2]);
            acc[3] = fmaf(wk, xa.w, acc[3]);
            acc[4] = fmaf(wk, xb.x, acc[4]);
            acc[5] = fmaf(wk, xb.y, acc[5]);
            acc[6] = fmaf(wk, xb.z, acc[6]);
            acc[7] = fmaf(wk, xb.w, acc[7]);
        }
        #pragma unroll
        for (int r = 0; r < RB; ++r) h0T[tid][r] = fmaxf(acc[r], 0.f);
    }
    __syncthreads();

    const int jj = tid & 127;
    const int half = tid >> 7;
    {
        float acc[RB];
        #pragma unroll
        for (int r = 0; r < RB; ++r) acc[r] = 0.f;
        #pragma unroll 4
        for (int t = 0; t < 128; ++t) {
            int k = half * 128 + t;
            float wk = mW1[k * 128 + jj];
            float4 ha = *(const float4*)&h0T[k][0];
            float4 hb = *(const float4*)&h0T[k][4];
            acc[0] = fmaf(wk, ha.x, acc[0]);
            acc[1] = fmaf(wk, ha.y, acc[1]);
            acc[2] = fmaf(wk, ha.z, acc[2]);
            acc[3] = fmaf(wk, ha.w, acc[3]);
            acc[4] = fmaf(wk, hb.x, acc[4]);
            acc[5] = fmaf(wk, hb.y, acc[5]);
            acc[6] = fmaf(wk, hb.z, acc[6]);
            acc[7] = fmaf(wk, hb.w, acc[7]);
        }
        if (half == 1) {
            #pragma unroll
            for (int r = 0; r < RB; ++r) part[jj][r] = acc[r];
        }
        __syncthreads();
        if (half == 0) {
            const float bias = mb1[jj];
            #pragma unroll
            for (int r = 0; r < RB; ++r)
                h1T[jj][r] = fmaxf(acc[r] + part[jj][r] + bias, 0.f);
        }
    }
    __syncthreads();

    if (tid < RB) {
        const int r = tid;
        float a0 = mb2[0], a1 = 0.f;
        #pragma unroll 8
        for (int k = 0; k < 128; k += 2) {
            a0 = fmaf(h1T[k][r],     mW2[k],     a0);
            a1 = fmaf(h1T[k + 1][r], mW2[k + 1], a1);
        }
        float a = a0 + a1;
        out[b0 + r] = 1.f / (1.f + __expf(-a));
    }
}

extern "C" void kernel_launch(void* const* d_in, const int* in_sizes, int n_in,
                              void* d_out, int out_size, void* d_ws, size_t ws_size,
                              hipStream_t stream) {
    (void)in_sizes; (void)n_in; (void)out_size; (void)ws_size;
    const int*   user_id    = (const int*)d_in[0];
    const int*   item_id    = (const int*)d_in[1];
    const int*   item_cat   = (const int*)d_in[2];
    const int*   item_dur   = (const int*)d_in[3];
    const float* user_dense = (const float*)d_in[4];
    const float* item_dense = (const float*)d_in[5];
    const int*   hist_seq   = (const int*)d_in[6];
    const float* user_W     = (const float*)d_in[7];
    const float* item_W     = (const float*)d_in[8];
    const float* cat_W      = (const float*)d_in[9];
    const float* dur_W      = (const float*)d_in[10];
    const float* hist_W     = (const float*)d_in[11];
    const float* aW0 = (const float*)d_in[12];
    const float* ab0 = (const float*)d_in[13];
    const float* aW1 = (const float*)d_in[14];
    const float* ab1 = (const float*)d_in[15];
    const float* aW2 = (const float*)d_in[16];
    const float* ab2 = (const float*)d_in[17];
    const float* mW0 = (const float*)d_in[18];
    const float* mb0 = (const float*)d_in[19];
    const float* mW1 = (const float*)d_in[20];
    const float* mb1 = (const float*)d_in[21];
    const float* mW2 = (const float*)d_in[22];
    const float* mb2 = (const float*)d_in[23];
    float* out = (float*)d_out;
    float* pooled_ws = (float*)d_ws;   // 4096*64 floats = 1 MB

    attn_kernel<<<4096, 256, 0, stream>>>(item_id, hist_seq, item_W, hist_W,
                                          aW0, ab0, aW1, ab1, aW2, ab2, pooled_ws);
    mlp_kernel<<<4096 / RB, 256, 0, stream>>>(user_id, item_id, item_cat, item_dur,
                                              user_dense, item_dense,
                                              user_W, item_W, cat_W, dur_W,
                                              mW0, mb0, mW1, mb1, mW2, mb2,
                                              pooled_ws, out);
}

// Round 5
// 436.801 us; speedup vs baseline: 1.1121x; 1.1121x over previous
//
#include <hip/hip_runtime.h>
#include <hip/hip_bf16.h>

#define L_SZ 200
#define RB 8

typedef __attribute__((ext_vector_type(8))) short short8;   // 8 bf16 = 4 VGPRs (MFMA A/B frag)
typedef __attribute__((ext_vector_type(4))) float floatx4;  // MFMA C/D frag

__device__ __forceinline__ unsigned short f2bf(float f) {
    unsigned int u = __float_as_uint(f);
    unsigned int r = (u + 0x7fffu + ((u >> 16) & 1u)) >> 16;
    return (unsigned short)r;
}
__device__ __forceinline__ unsigned int pkrn(float a, float b) {
    float2 f; f.x = a; f.y = b;
    __hip_bfloat162 h = __float22bfloat162_rn(f);
    union { __hip_bfloat162 h2; unsigned int u; } v; v.h2 = h;
    return v.u;
}
__device__ __forceinline__ short8 pack8(float4 lo, float4 hi) {
    union { uint4 u; short8 s; } t;
    t.u.x = pkrn(lo.x, lo.y); t.u.y = pkrn(lo.z, lo.w);
    t.u.z = pkrn(hi.x, hi.y); t.u.w = pkrn(hi.z, hi.w);
    return t.s;
}
__device__ __forceinline__ float wave_sum64(float v) {
    #pragma unroll
    for (int m = 1; m <= 32; m <<= 1) v += __shfl_xor(v, m, 64);
    return v;
}
__device__ __forceinline__ float wave_max64(float v) {
    #pragma unroll
    for (int m = 1; m <= 32; m <<= 1) v = fmaxf(v, __shfl_xor(v, m, 64));
    return v;
}

// One block per batch element, 4 waves. Layer0 folded to 64x64 W_eff.
// R5: no Hs archive. A-frags gathered from hist_W INSIDE the main loop
// (transient regs, packed immediately); pooling re-gathers rows (L3-hot)
// and butterfly-reduces over the 16 c-lanes. Uniform 4-tile/wave control
// flow with wave-uniform guards (NO break -> arrays stay promoted).
// WeT/W1T/scr all use the XOR-8-group swizzle: <=2-way banks per
// quarter-wave on every b128 access.
__global__ __launch_bounds__(256, 4) void attn_kernel(
    const int* __restrict__ item_id, const int* __restrict__ hist_seq,
    const float* __restrict__ item_W, const float* __restrict__ hist_W,
    const float* __restrict__ aW0, const float* __restrict__ ab0,
    const float* __restrict__ aW1, const float* __restrict__ ab1,
    const float* __restrict__ aW2, const float* __restrict__ ab2,
    float* __restrict__ pooled_ws)
{
    __shared__ __align__(16) unsigned char smem[22336];
    unsigned short* WeT = (unsigned short*)(smem);           // 64x64 bf16 swizzled, 8192 B
    unsigned short* W1T = (unsigned short*)(smem + 8192);    // 32x64 bf16 swizzled, 4096 B
    unsigned short* scr = (unsigned short*)(smem + 12288);   // 4 x 16x64 bf16, 8192 B
    float* scores = (float*)(smem + 20480);                  // 200 f32
    float* cbp    = (float*)(smem + 21280);                  // 256 f32 (later: pools)
    float* red    = (float*)(smem + 22304);                  // 8 f32

    const int tid  = threadIdx.x;
    const int w    = tid >> 6;
    const int lane = tid & 63;
    const int c    = lane & 15, q = lane >> 4;
    const int b    = blockIdx.x;
    const int* seqp = hist_seq + b * L_SZ;
    const float* iW = item_W + (size_t)item_id[b] * 64;

    // ---- seq prefetch for this lane's 4 tile-rows (row mt*16+c, clamped) ----
    int seqr[4];
    #pragma unroll
    for (int t = 0; t < 4; ++t) {
        int row = (w + 4 * t) * 16 + c;
        int rc  = (row < L_SZ) ? row : (L_SZ - 1);
        seqr[t] = seqp[rc];
    }

    // ---- WeT[j][k] = aW0[k][j] + aW0[192+k][j] + iemb[k]*aW0[128+k][j] ----
    for (int u = tid; u < 512; u += 256) {
        int j = u >> 3, k8 = u & 7;
        float4 ia = *(const float4*)(iW + k8 * 8);
        float4 ib = *(const float4*)(iW + k8 * 8 + 4);
        float ie[8] = {ia.x, ia.y, ia.z, ia.w, ib.x, ib.y, ib.z, ib.w};
        float v[8];
        #pragma unroll
        for (int i = 0; i < 8; ++i) {
            int k = k8 * 8 + i;
            v[i] = aW0[k * 64 + j] + aW0[(192 + k) * 64 + j]
                 + ie[i] * aW0[(128 + k) * 64 + j];
        }
        uint4 pk;
        pk.x = pkrn(v[0], v[1]); pk.y = pkrn(v[2], v[3]);
        pk.z = pkrn(v[4], v[5]); pk.w = pkrn(v[6], v[7]);
        *(uint4*)(WeT + j * 64 + (k8 ^ (j & 7)) * 8) = pk;
    }
    // ---- W1T[n][k] = aW1[k][n], swizzled; exactly one chunk per thread ----
    {
        int n = tid >> 3, k8 = tid & 7;
        float v[8];
        #pragma unroll
        for (int i = 0; i < 8; ++i) v[i] = aW1[(k8 * 8 + i) * 32 + n];
        uint4 pk;
        pk.x = pkrn(v[0], v[1]); pk.y = pkrn(v[2], v[3]);
        pk.z = pkrn(v[4], v[5]); pk.w = pkrn(v[6], v[7]);
        *(uint4*)(W1T + n * 64 + (k8 ^ (n & 7)) * 8) = pk;
    }
    // ---- cb partials: wave w covers k in [16w, 16w+16) ----
    {
        float cpart = 0.f;
        #pragma unroll 4
        for (int t = 0; t < 16; ++t) {
            int k = w * 16 + t;
            cpart = fmaf(iW[k], aW0[(64 + k) * 64 + lane] - aW0[(192 + k) * 64 + lane], cpart);
        }
        cbp[w * 64 + lane] = cpart;
    }
    float ab1r[2], aw2r[2];
    #pragma unroll
    for (int nt = 0; nt < 2; ++nt) {
        ab1r[nt] = ab1[nt * 16 + c];
        aw2r[nt] = aW2[nt * 16 + c];
    }
    const float ab2s = ab2[0];
    __syncthreads();

    float cbr[4];
    #pragma unroll
    for (int nt = 0; nt < 4; ++nt) {
        int j = nt * 16 + c;
        cbr[nt] = ab0[j] + ((cbp[j] + cbp[64 + j]) + (cbp[128 + j] + cbp[192 + j]));
    }

    unsigned short* scrw = scr + w * (16 * 64);
    const floatx4 zf = {0.f, 0.f, 0.f, 0.f};

    // ---- main loop: barrier-free. gather -> L0 MFMA -> scr -> L1 MFMA -> score ----
    #pragma unroll
    for (int t = 0; t < 4; ++t) {
        const int mt = w + 4 * t;                  // wave-uniform
        if (mt * 16 < L_SZ) {                      // wave-uniform guard (no break!)
            const float* hrow = hist_W + (size_t)seqr[t] * 64;
            float4 ga0 = *(const float4*)(hrow + q * 8);
            float4 ga1 = *(const float4*)(hrow + q * 8 + 4);
            float4 gb0 = *(const float4*)(hrow + 32 + q * 8);
            float4 gb1 = *(const float4*)(hrow + 32 + q * 8 + 4);
            short8 a0 = pack8(ga0, ga1);
            short8 a1 = pack8(gb0, gb1);

            floatx4 acc0[4] = {zf, zf, zf, zf};
            #pragma unroll
            for (int nt = 0; nt < 4; ++nt) {
                const unsigned short* wrow = WeT + (nt * 16 + c) * 64;
                short8 b0 = *(const short8*)(wrow + ((0 * 4 + q) ^ (c & 7)) * 8);
                short8 b1 = *(const short8*)(wrow + ((1 * 4 + q) ^ (c & 7)) * 8);
                acc0[nt] = __builtin_amdgcn_mfma_f32_16x16x32_bf16(a0, b0, acc0[nt], 0, 0, 0);
                acc0[nt] = __builtin_amdgcn_mfma_f32_16x16x32_bf16(a1, b1, acc0[nt], 0, 0, 0);
            }
            // epilogue: +cb, relu, bf16; C-layout (col=c,row=q*4+r) -> swizzled scr
            #pragma unroll
            for (int nt = 0; nt < 4; ++nt)
                #pragma unroll
                for (int r = 0; r < 4; ++r) {
                    float h = fmaxf(acc0[nt][r] + cbr[nt], 0.f);
                    int row = q * 4 + r;
                    int gp = (2 * nt + (c >> 3)) ^ (row & 7);
                    scrw[row * 64 + gp * 8 + (c & 7)] = f2bf(h);
                }
            floatx4 acc1[2] = {zf, zf};
            #pragma unroll
            for (int ks = 0; ks < 2; ++ks) {
                short8 af = *(const short8*)(scrw + c * 64 + ((4 * ks + q) ^ (c & 7)) * 8);
                short8 w0 = *(const short8*)(W1T + c * 64 + ((4 * ks + q) ^ (c & 7)) * 8);
                short8 w1 = *(const short8*)(W1T + (16 + c) * 64 + ((4 * ks + q) ^ (c & 7)) * 8);
                acc1[0] = __builtin_amdgcn_mfma_f32_16x16x32_bf16(af, w0, acc1[0], 0, 0, 0);
                acc1[1] = __builtin_amdgcn_mfma_f32_16x16x32_bf16(af, w1, acc1[1], 0, 0, 0);
            }
            // layer2: relu -> *aW2 -> butterfly over the 16 c-lanes
            float s[4];
            #pragma unroll
            for (int r = 0; r < 4; ++r)
                s[r] = fmaxf(acc1[0][r] + ab1r[0], 0.f) * aw2r[0]
                     + fmaxf(acc1[1][r] + ab1r[1], 0.f) * aw2r[1];
            #pragma unroll
            for (int m = 1; m <= 8; m <<= 1)
                #pragma unroll
                for (int r = 0; r < 4; ++r) s[r] += __shfl_xor(s[r], m, 64);
            if (c == 0) {
                #pragma unroll
                for (int r = 0; r < 4; ++r) {
                    int l = mt * 16 + q * 4 + r;
                    if (l < L_SZ) scores[l] = s[r] + ab2s;   // mask applied in softmax
                }
            }
        }
    }
    __syncthreads();

    // ---- masked softmax over 200 scores (mask via global seq, L2-hot) ----
    float s0 = -3.0e38f;
    if (tid < L_SZ) {
        int sq = seqp[tid];
        s0 = (sq == 0) ? -1.0e9f : scores[tid];
    }
    float mx = wave_max64(s0);
    if (lane == 0) red[w] = mx;
    __syncthreads();
    mx = fmaxf(fmaxf(red[0], red[1]), fmaxf(red[2], red[3]));
    float e = (tid < L_SZ) ? __expf(s0 - mx) : 0.f;
    float sm = wave_sum64(e);
    if (lane == 0) red[4 + w] = sm;
    __syncthreads();
    const float winv = 1.f / ((red[4] + red[5]) + (red[6] + red[7]));
    if (tid < L_SZ) scores[tid] = e * winv;
    __syncthreads();

    // ---- pooled[j]: re-gather this lane's rows (fp32, L3-hot), weight, reduce ----
    float pl[16];
    #pragma unroll
    for (int i = 0; i < 16; ++i) pl[i] = 0.f;
    #pragma unroll
    for (int t = 0; t < 4; ++t) {
        int row = (w + 4 * t) * 16 + c;
        if (row < L_SZ) {
            float wt = scores[row];
            const float* hrow = hist_W + (size_t)seqr[t] * 64;
            float4 ga0 = *(const float4*)(hrow + q * 8);
            float4 ga1 = *(const float4*)(hrow + q * 8 + 4);
            float4 gb0 = *(const float4*)(hrow + 32 + q * 8);
            float4 gb1 = *(const float4*)(hrow + 32 + q * 8 + 4);
            pl[0]  = fmaf(wt, ga0.x, pl[0]);  pl[1]  = fmaf(wt, ga0.y, pl[1]);
            pl[2]  = fmaf(wt, ga0.z, pl[2]);  pl[3]  = fmaf(wt, ga0.w, pl[3]);
            pl[4]  = fmaf(wt, ga1.x, pl[4]);  pl[5]  = fmaf(wt, ga1.y, pl[5]);
            pl[6]  = fmaf(wt, ga1.z, pl[6]);  pl[7]  = fmaf(wt, ga1.w, pl[7]);
            pl[8]  = fmaf(wt, gb0.x, pl[8]);  pl[9]  = fmaf(wt, gb0.y, pl[9]);
            pl[10] = fmaf(wt, gb0.z, pl[10]); pl[11] = fmaf(wt, gb0.w, pl[11]);
            pl[12] = fmaf(wt, gb1.x, pl[12]); pl[13] = fmaf(wt, gb1.y, pl[13]);
            pl[14] = fmaf(wt, gb1.z, pl[14]); pl[15] = fmaf(wt, gb1.w, pl[15]);
        }
    }
    // butterfly-reduce over the 16 c-lanes (xor 1,2,4,8)
    #pragma unroll
    for (int m = 1; m <= 8; m <<= 1)
        #pragma unroll
        for (int i = 0; i < 16; ++i) pl[i] += __shfl_xor(pl[i], m, 64);
    float* pools = cbp;   // cbp consumed into cbr long ago
    if (c == 0) {
        float4 v0 = {pl[0], pl[1], pl[2], pl[3]};
        float4 v1 = {pl[4], pl[5], pl[6], pl[7]};
        float4 v2 = {pl[8], pl[9], pl[10], pl[11]};
        float4 v3 = {pl[12], pl[13], pl[14], pl[15]};
        *(float4*)&pools[w * 64 + q * 8]      = v0;
        *(float4*)&pools[w * 64 + q * 8 + 4]  = v1;
        *(float4*)&pools[w * 64 + 32 + q * 8]     = v2;
        *(float4*)&pools[w * 64 + 32 + q * 8 + 4] = v3;
    }
    __syncthreads();
    if (tid < 64) {
        pooled_ws[(size_t)b * 64 + tid] =
            (pools[tid] + pools[64 + tid]) + (pools[128 + tid] + pools[192 + tid]);
    }
}

// Main MLP: 244 -> 256 -> 128 -> 1 -> sigmoid. One block per RB=8 rows.
__global__ __launch_bounds__(256) void mlp_kernel(
    const int* __restrict__ user_id, const int* __restrict__ item_id,
    const int* __restrict__ item_cat, const int* __restrict__ item_dur,
    const float* __restrict__ user_dense, const float* __restrict__ item_dense,
    const float* __restrict__ user_W, const float* __restrict__ item_W,
    const float* __restrict__ cat_W, const float* __restrict__ dur_W,
    const float* __restrict__ mW0, const float* __restrict__ mb0,
    const float* __restrict__ mW1, const float* __restrict__ mb1,
    const float* __restrict__ mW2, const float* __restrict__ mb2,
    const float* __restrict__ pooled_ws, float* __restrict__ out)
{
    __shared__ __align__(16) float xT[244][RB];
    __shared__ __align__(16) float h0T[256][RB];
    __shared__ __align__(16) float h1T[128][RB];
    __shared__ __align__(16) float part[128][RB];

    const int tid = threadIdx.x;
    const int b0 = blockIdx.x * RB;

    for (int idx = tid; idx < 244 * RB; idx += 256) {
        int r = idx / 244;
        int c = idx - r * 244;
        int b = b0 + r;
        float v;
        if (c < 64)       v = user_W[(size_t)user_id[b] * 64 + c];
        else if (c < 128) v = item_W[(size_t)item_id[b] * 64 + (c - 64)];
        else if (c < 144) v = cat_W[item_cat[b] * 16 + (c - 128)];
        else if (c < 152) v = dur_W[item_dur[b] * 8 + (c - 144)];
        else if (c < 177) v = user_dense[b * 25 + (c - 152)];
        else if (c < 180) v = item_dense[b * 3 + (c - 177)];
        else              v = pooled_ws[(size_t)b * 64 + (c - 180)];
        xT[c][r] = v;
    }
    __syncthreads();

    {
        float acc[RB];
        const float bias = mb0[tid];
        #pragma unroll
        for (int r = 0; r < RB; ++r) acc[r] = bias;
        #pragma unroll 4
        for (int k = 0; k < 244; ++k) {
            float wk = mW0[k * 256 + tid];
            float4 xa = *(const float4*)&xT[k][0];
            float4 xb = *(const float4*)&xT[k][4];
            acc[0] = fmaf(wk, xa.x, acc[0]);
            acc[1] = fmaf(wk, xa.y, acc[1]);
            acc[2] = fmaf(wk, xa.z, acc[2]);
            acc[3] = fmaf(wk, xa.w, acc[3]);
            acc[4] = fmaf(wk, xb.x, acc[4]);
            acc[5] = fmaf(wk, xb.y, acc[5]);
            acc[6] = fmaf(wk, xb.z, acc[6]);
            acc[7] = fmaf(wk, xb.w, acc[7]);
        }
        #pragma unroll
        for (int r = 0; r < RB; ++r) h0T[tid][r] = fmaxf(acc[r], 0.f);
    }
    __syncthreads();

    const int jj = tid & 127;
    const int half = tid >> 7;
    {
        float acc[RB];
        #pragma unroll
        for (int r = 0; r < RB; ++r) acc[r] = 0.f;
        #pragma unroll 4
        for (int t = 0; t < 128; ++t) {
            int k = half * 128 + t;
            float wk = mW1[k * 128 + jj];
            float4 ha = *(const float4*)&h0T[k][0];
            float4 hb = *(const float4*)&h0T[k][4];
            acc[0] = fmaf(wk, ha.x, acc[0]);
            acc[1] = fmaf(wk, ha.y, acc[1]);
            acc[2] = fmaf(wk, ha.z, acc[2]);
            acc[3] = fmaf(wk, ha.w, acc[3]);
            acc[4] = fmaf(wk, hb.x, acc[4]);
            acc[5] = fmaf(wk, hb.y, acc[5]);
            acc[6] = fmaf(wk, hb.z, acc[6]);
            acc[7] = fmaf(wk, hb.w, acc[7]);
        }
        if (half == 1) {
            #pragma unroll
            for (int r = 0; r < RB; ++r) part[jj][r] = acc[r];
        }
        __syncthreads();
        if (half == 0) {
            const float bias = mb1[jj];
            #pragma unroll
            for (int r = 0; r < RB; ++r)
                h1T[jj][r] = fmaxf(acc[r] + part[jj][r] + bias, 0.f);
        }
    }
    __syncthreads();

    if (tid < RB) {
        const int r = tid;
        float a0 = mb2[0], a1 = 0.f;
        #pragma unroll 8
        for (int k = 0; k < 128; k += 2) {
            a0 = fmaf(h1T[k][r],     mW2[k],     a0);
            a1 = fmaf(h1T[k + 1][r], mW2[k + 1], a1);
        }
        float a = a0 + a1;
        out[b0 + r] = 1.f / (1.f + __expf(-a));
    }
}

extern "C" void kernel_launch(void* const* d_in, const int* in_sizes, int n_in,
                              void* d_out, int out_size, void* d_ws, size_t ws_size,
                              hipStream_t stream) {
    (void)in_sizes; (void)n_in; (void)out_size; (void)ws_size;
    const int*   user_id    = (const int*)d_in[0];
    const int*   item_id    = (const int*)d_in[1];
    const int*   item_cat   = (const int*)d_in[2];
    const int*   item_dur   = (const int*)d_in[3];
    const float* user_dense = (const float*)d_in[4];
    const float* item_dense = (const float*)d_in[5];
    const int*   hist_seq   = (const int*)d_in[6];
    const float* user_W     = (const float*)d_in[7];
    const float* item_W     = (const float*)d_in[8];
    const float* cat_W      = (const float*)d_in[9];
    const float* dur_W      = (const float*)d_in[10];
    const float* hist_W     = (const float*)d_in[11];
    const float* aW0 = (const float*)d_in[12];
    const float* ab0 = (const float*)d_in[13];
    const float* aW1 = (const float*)d_in[14];
    const float* ab1 = (const float*)d_in[15];
    const float* aW2 = (const float*)d_in[16];
    const float* ab2 = (const float*)d_in[17];
    const float* mW0 = (const float*)d_in[18];
    const float* mb0 = (const float*)d_in[19];
    const float* mW1 = (const float*)d_in[20];
    const float* mb1 = (const float*)d_in[21];
    const float* mW2 = (const float*)d_in[22];
    const float* mb2 = (const float*)d_in[23];
    float* out = (float*)d_out;
    float* pooled_ws = (float*)d_ws;   // 4096*64 floats = 1 MB

    attn_kernel<<<4096, 256, 0, stream>>>(item_id, hist_seq, item_W, hist_W,
                                          aW0, ab0, aW1, ab1, aW2, ab2, pooled_ws);
    mlp_kernel<<<4096 / RB, 256, 0, stream>>>(user_id, item_id, item_cat, item_dur,
                                              user_dense, item_dense,
                                              user_W, item_W, cat_W, dur_W,
                                              mW0, mb0, mW1, mb1, mW2, mb2,
                                              pooled_ws, out);
}